// Round 3
// baseline (458.879 us; speedup 1.0000x reference)
//
#include <hip/hip_runtime.h>

// 3x3 conv, stride 1, pad 1, NCHW, C=1. eff_w[i][j] = weight[i][j]*kx[i]*kx[j],
// kx = [den, 1, den]. x: (16,1,2048,2048) fp32 -> out same shape fp32.
//
// Memory-bound stencil. Each thread: 4(w) x 16(h) output tile, sliding
// 3-row register buffers (read amp = 18/16 = 1.125x). Horizontal halo via
// wave shuffles (lanes hold consecutive float4 chunks of the same row);
// only lanes 0/63 do an exec-masked scalar edge load. Nontemporal stores
// preserve L2 for the inter-rowgroup input halo.

#define IMG_W 2048
#define IMG_H 2048
#define BATCH 16
#define RPT 16                 // rows per thread
#define WCHUNKS (IMG_W / 4)    // 512 float4 chunks per row
#define ROWGRPS (IMG_H / RPT)  // 128 row-groups

typedef float f4 __attribute__((ext_vector_type(4)));  // native vector: ok for nontemporal builtins

__global__ __launch_bounds__(256) void conv3x3_kernel(
    const float* __restrict__ x,
    const float* __restrict__ weight,
    const float* __restrict__ den,
    float* __restrict__ out)
{
    const int tid    = blockIdx.x * 256 + threadIdx.x;
    const int wchunk = tid & (WCHUNKS - 1);        // 9 bits
    const int rowgrp = (tid >> 9) & (ROWGRPS - 1); // 7 bits
    const int b      = tid >> 16;
    const int lane   = threadIdx.x & 63;

    // effective 3x3 weights (scalar broadcast)
    const float d = den[0];
    const float k[3] = {d, 1.0f, d};
    float wgt[3][3];
#pragma unroll
    for (int i = 0; i < 3; ++i)
#pragma unroll
        for (int j = 0; j < 3; ++j)
            wgt[i][j] = weight[i * 3 + j] * k[i] * k[j];

    const float* xb = x   + (size_t)b * IMG_H * IMG_W;
    float*       ob = out + (size_t)b * IMG_H * IMG_W;
    const int w0 = wchunk * 4;
    const int h0 = rowgrp * RPT;
    const bool has_l = (w0 > 0);             // only consulted on lane 0
    const bool has_r = (w0 + 4 < IMG_W);     // only consulted on lane 63

    // row buffer: v[0]=col w0-1, v[1..4]=cols w0..w0+3, v[5]=col w0+4
    // h is wave-uniform (rowgrp/b constant across the 64-lane span), so the
    // bounds branch is non-divergent and shuffles see all lanes.
    auto load_row = [&](int h, float v[6]) {
        if ((unsigned)h >= IMG_H) {
#pragma unroll
            for (int i = 0; i < 6; ++i) v[i] = 0.0f;
            return;
        }
        const float* r = xb + (size_t)h * IMG_W + w0;
        const f4 c = *(const f4*)r;
        v[1] = c.x; v[2] = c.y; v[3] = c.z; v[4] = c.w;
        float left  = __shfl_up(c.w, 1);   // lane i-1's col w0-1
        float right = __shfl_down(c.x, 1); // lane i+1's col w0+4
        if (lane == 0)  left  = has_l ? r[-1] : 0.0f;  // image/wave edge
        if (lane == 63) right = has_r ? r[4]  : 0.0f;
        v[0] = left; v[5] = right;
    };

    float ra[6], rb[6], rc[6];
    load_row(h0 - 1, ra);  // top padding -> zeros when h0==0
    load_row(h0,     rb);

#pragma unroll
    for (int rr = 0; rr < RPT; ++rr) {
        load_row(h0 + rr + 1, rc);  // bottom padding handled inside

        f4 o;
#pragma unroll
        for (int j = 0; j < 4; ++j) {
            o[j] = wgt[0][0]*ra[j] + wgt[0][1]*ra[j+1] + wgt[0][2]*ra[j+2]
                 + wgt[1][0]*rb[j] + wgt[1][1]*rb[j+1] + wgt[1][2]*rb[j+2]
                 + wgt[2][0]*rc[j] + wgt[2][1]*rc[j+1] + wgt[2][2]*rc[j+2];
        }
        __builtin_nontemporal_store(o, (f4*)(ob + (size_t)(h0 + rr) * IMG_W + w0));

#pragma unroll
        for (int i = 0; i < 6; ++i) { ra[i] = rb[i]; rb[i] = rc[i]; }
    }
}

extern "C" void kernel_launch(void* const* d_in, const int* in_sizes, int n_in,
                              void* d_out, int out_size, void* d_ws, size_t ws_size,
                              hipStream_t stream) {
    const float* x      = (const float*)d_in[0];
    const float* weight = (const float*)d_in[1];
    const float* den    = (const float*)d_in[2];
    float*       out    = (float*)d_out;

    const int total  = WCHUNKS * ROWGRPS * BATCH;  // 1,048,576 threads
    const int blocks = total / 256;                // 4096
    conv3x3_kernel<<<blocks, 256, 0, stream>>>(x, weight, den, out);
}